// Round 5
// baseline (427.297 us; speedup 1.0000x reference)
//
#include <hip/hip_runtime.h>
#include <hip/hip_bf16.h>

// SAGAN self-attention: B=16, C=256, H=W=64, HW=4096, KEYS=1024, C8=32, C2=128
// Pipeline: prep_w -> proj (theta/phi/g GEMM) -> pool_phi/pool_g -> flash attn -> final conv+residual

typedef short short8 __attribute__((ext_vector_type(8)));
typedef short short4v __attribute__((ext_vector_type(4)));
typedef float f32x4  __attribute__((ext_vector_type(4)));

#define MFMA16(a, b, c) __builtin_amdgcn_mfma_f32_16x16x32_bf16(a, b, c, 0, 0, 0)

__device__ __forceinline__ short f2bf(float f) {
    union { float f; unsigned u; } v; v.f = f;
    unsigned r = v.u + 0x7FFFu + ((v.u >> 16) & 1u);   // RNE
    return (short)(r >> 16);
}
__device__ __forceinline__ float bf2f(short s) {
    union { unsigned u; float f; } v; v.u = ((unsigned)(unsigned short)s) << 16;
    return v.f;
}

// K=16 bf16 MFMA. A/B: 4 bf16/lane, element i -> row/col = lane&15, k = 4*(lane>>4)+i.
// Use BUILTINS so the compiler models MFMA hazards (inline-asm MFMA gets no
// s_nop insertion -> VALU-write->MFMA-read hazard corrupted v2's results).
#if __has_builtin(__builtin_amdgcn_mfma_f32_16x16x16bf16_1k)
__device__ __forceinline__ void mfma_k16(short4v a, short4v b, f32x4& c) {
    c = __builtin_amdgcn_mfma_f32_16x16x16bf16_1k(a, b, c, 0, 0, 0);
}
#elif __has_builtin(__builtin_amdgcn_mfma_f32_16x16x16_bf16)
__device__ __forceinline__ void mfma_k16(short4v a, short4v b, f32x4& c) {
    c = __builtin_amdgcn_mfma_f32_16x16x16_bf16(a, b, c, 0, 0, 0);
}
#else
__device__ __forceinline__ void mfma_k16(short4v a, short4v b, f32x4& c) {
    // last-resort asm: pad VALU->MFMA-read and MFMA->VALU-read hazards manually
    asm volatile("s_nop 3\n\t"
                 "v_mfma_f32_16x16x16_bf16 %0, %1, %2, %0\n\t"
                 "s_nop 7\n\t"
                 "s_nop 3"
                 : "+v"(c) : "v"(a), "v"(b));
}
#endif

// ---------------------------------------------------------------- prep_w
// w_bf [192][256] bf16: rows 0-31 theta, 32-63 phi, 64-191 g. wf_bf [256][128].
__global__ __launch_bounds__(256) void prep_w(const float* wt, const float* wp,
                                              const float* wg, const float* wf,
                                              short* w_bf, short* wf_bf) {
    int idx = blockIdx.x * 256 + threadIdx.x;
    if (idx < 192 * 256) {
        int o = idx >> 8, c = idx & 255;
        float v = (o < 32) ? wt[o * 256 + c]
                : (o < 64) ? wp[(o - 32) * 256 + c]
                           : wg[(o - 64) * 256 + c];
        w_bf[idx] = f2bf(v);
    } else {
        int j = idx - 192 * 256;
        if (j < 256 * 128) wf_bf[j] = f2bf(wf[j]);
    }
}

// ---------------------------------------------------------------- proj
// out[o][p] = sum_c W[o][c] * x[c][p] for 64-pixel tile, all 192 out-channels.
// x staged in LDS transposed to [p][c] bf16 (pitch 264 => 16B-aligned b128 reads).
__global__ __launch_bounds__(256) void proj(const float* __restrict__ x,
                                            const short* __restrict__ w_bf,
                                            short* __restrict__ theta,
                                            short* __restrict__ phiF,
                                            short* __restrict__ gF) {
    __shared__ short xl[64 * 264];
    const int t = threadIdx.x;
    const int b = blockIdx.x >> 6;
    const int pb = (blockIdx.x & 63) << 6;
    const int p = t & 63;

    // stage: each thread packs 2 channels (c0, c0+1) for its pixel, 32 iters
    #pragma unroll
    for (int i = 0; i < 32; ++i) {
        int cp = (t >> 6) + (i << 2);          // 0..127 channel-pair index
        int c0 = cp << 1;
        float v0 = x[(b * 256 + c0) * 4096 + pb + p];
        float v1 = x[(b * 256 + c0 + 1) * 4096 + pb + p];
        unsigned pk = ((unsigned)(unsigned short)f2bf(v0)) |
                      (((unsigned)(unsigned short)f2bf(v1)) << 16);
        *(unsigned*)&xl[p * 264 + c0] = pk;
    }
    __syncthreads();

    const int lane = t & 63, w = t >> 6, G = lane >> 4, l15 = lane & 15;

    short8 af[3][8];                            // wave w owns out-rows 48w..48w+47
    #pragma unroll
    for (int j = 0; j < 3; ++j) {
        int ot = 3 * w + j;
        #pragma unroll
        for (int kt = 0; kt < 8; ++kt)
            af[j][kt] = *(const short8*)(w_bf + (16 * ot + l15) * 256 + 32 * kt + 8 * G);
    }
    f32x4 acc[3][4];
    #pragma unroll
    for (int j = 0; j < 3; ++j)
        #pragma unroll
        for (int n = 0; n < 4; ++n) acc[j][n] = (f32x4){0.f, 0.f, 0.f, 0.f};

    #pragma unroll
    for (int nt = 0; nt < 4; ++nt) {
        #pragma unroll
        for (int kt = 0; kt < 8; ++kt) {
            short8 bfr = *(const short8*)(xl + (16 * nt + l15) * 264 + 32 * kt + 8 * G);
            #pragma unroll
            for (int j = 0; j < 3; ++j)
                acc[j][nt] = MFMA16(af[j][kt], bfr, acc[j][nt]);
        }
    }

    // epilogue: D layout col=lane&15 (pixel), row=4G+r (out-channel)
    #pragma unroll
    for (int j = 0; j < 3; ++j) {
        int ot = 3 * w + j;
        #pragma unroll
        for (int nt = 0; nt < 4; ++nt) {
            int pp = pb + 16 * nt + l15;
            #pragma unroll
            for (int r = 0; r < 4; ++r) {
                int o = 16 * ot + 4 * G + r;
                short v = f2bf(acc[j][nt][r]);
                if (o < 32)      theta[(b * 4096 + pp) * 32 + o] = v;
                else if (o < 64) phiF [(b * 4096 + pp) * 32 + (o - 32)] = v;
                else             gF   [(b * 4096 + pp) * 128 + (o - 64)] = v;
            }
        }
    }
}

// ---------------------------------------------------------------- pool_phi
// phiF [b][4096][32] -> phi_t [b][1024][32] (key-major, K-contiguous for QK A-frag)
__global__ __launch_bounds__(256) void pool_phi(const short* __restrict__ phiF,
                                                short* __restrict__ phi_t) {
    int t = threadIdx.x;
    int b = blockIdx.x >> 7;
    int kg = blockIdx.x & 127;
    int c = t & 31;
    int ko = kg * 8 + (t >> 5);
    int kh = ko >> 5, kw = ko & 31;
    int p00 = kh * 128 + kw * 2;
    const short* base = phiF + (b * 4096 + p00) * 32 + c;
    float m = bf2f(base[0]);
    m = fmaxf(m, bf2f(base[32]));
    m = fmaxf(m, bf2f(base[64 * 32]));
    m = fmaxf(m, bf2f(base[65 * 32]));
    phi_t[(b * 1024 + ko) * 32 + c] = f2bf(m);
}

// ---------------------------------------------------------------- pool_g
// gF [b][4096][128] -> g_cm [b][128][1024] (channel-major, key-contiguous for PV B-frag)
__global__ __launch_bounds__(256) void pool_g(const short* __restrict__ gF,
                                              short* __restrict__ g_cm) {
    __shared__ short gp[32 * 132];
    int t = threadIdx.x;
    int b = blockIdx.x >> 5;
    int kh = blockIdx.x & 31;
    int d = t & 127;
    int half = t >> 7;
    #pragma unroll
    for (int i = 0; i < 16; ++i) {
        int kw = i * 2 + half;
        int p00 = kh * 128 + kw * 2;
        const short* base = gF + (b * 4096 + p00) * 128 + d;
        float m = bf2f(base[0]);
        m = fmaxf(m, bf2f(base[128]));
        m = fmaxf(m, bf2f(base[64 * 128]));
        m = fmaxf(m, bf2f(base[65 * 128]));
        gp[kw * 132 + d] = f2bf(m);
    }
    __syncthreads();
    int dd = t >> 1, hf = t & 1;
    short8 lo, hi;
    #pragma unroll
    for (int m2 = 0; m2 < 8; ++m2) lo[m2] = gp[(hf * 16 + m2) * 132 + dd];
    #pragma unroll
    for (int m2 = 0; m2 < 8; ++m2) hi[m2] = gp[(hf * 16 + 8 + m2) * 132 + dd];
    short* outp = g_cm + (b * 128 + dd) * 1024 + kh * 32 + hf * 16;
    *(short8*)outp = lo;
    *(short8*)(outp + 8) = hi;
}

// ---------------------------------------------------------------- flash (v3: all-register P, builtin MFMAs)
// Swapped QK^T: S = mfma_16x16x32(A=phi[16 keys][32c], B=theta[16 q][32c]).
// D layout puts S[key=4G+r][q=l15] in lane (l15,G) -- exactly the A-frag of
// the K=16 bf16 MFMA (row=l15, k=4G+i). exp + plain-C bf16 pack -> PV directly.
// No LDS, no shuffles in the loop; 1-deep manual prefetch of phi+g chunks.
__global__ __launch_bounds__(256, 4) void flash(const short* __restrict__ theta,
                                                const short* __restrict__ phi_t,
                                                const short* __restrict__ g_cm,
                                                short* __restrict__ ag) {
    const int t = threadIdx.x;
    const int b = blockIdx.x >> 6;
    const int qb = (blockIdx.x & 63) << 6;
    const int lane = t & 63, w = t >> 6, G = lane >> 4, l15 = lane & 15;

    // theta as B-frag: lane l15 = q col, c = 8G..8G+7
    const short8 tb = *(const short8*)(theta + ((b * 4096) + qb + 16 * w + l15) * 32 + 8 * G);

    f32x4 acc[8];
    #pragma unroll
    for (int n = 0; n < 8; ++n) acc[n] = (f32x4){0.f, 0.f, 0.f, 0.f};
    float rs = 0.f;
    const f32x4 z = {0.f, 0.f, 0.f, 0.f};

    const short* phiB = phi_t + (b * 1024 + l15) * 32 + 8 * G;   // + kc*512
    const short* gB   = g_cm + (b * 128 + l15) * 1024 + 4 * G;   // + n*16384 + kc*16

    // prologue: prefetch chunk 0
    short8 pf = *(const short8*)(phiB);
    short4v gb[8];
    #pragma unroll
    for (int n = 0; n < 8; ++n) gb[n] = *(const short4v*)(gB + n * 16384);

    #pragma unroll 2
    for (int kc = 0; kc < 64; ++kc) {
        const int kn = (kc + 1) & 63;            // wraps to 0 on last iter (harmless)
        // prefetch next chunk
        short8 pf_n = *(const short8*)(phiB + kn * 512);
        short4v gb_n[8];
        #pragma unroll
        for (int n = 0; n < 8; ++n) gb_n[n] = *(const short4v*)(gB + n * 16384 + kn * 16);

        // S for 16 keys: lane (l15,G) gets P[q=l15][k=4G+r]
        f32x4 s = MFMA16(pf, tb, z);
        float e0 = __expf(s[0]);
        float e1 = __expf(s[1]);
        float e2 = __expf(s[2]);
        float e3 = __expf(s[3]);
        rs += (e0 + e1) + (e2 + e3);
        short4v p4;                              // P A-frag, compiler-visible pack
        p4[0] = f2bf(e0);
        p4[1] = f2bf(e1);
        p4[2] = f2bf(e2);
        p4[3] = f2bf(e3);

        #pragma unroll
        for (int n = 0; n < 8; ++n) mfma_k16(p4, gb[n], acc[n]);

        pf = pf_n;
        #pragma unroll
        for (int n = 0; n < 8; ++n) gb[n] = gb_n[n];
    }

    // row-sum: combine the 4 G-groups holding query l15
    rs += __shfl_xor(rs, 16);
    rs += __shfl_xor(rs, 32);
    // acc D-layout holds rows q = 4G+r -> gather those sums (lane 4G+r has l15==4G+r)
    float rq[4];
    #pragma unroll
    for (int r = 0; r < 4; ++r) rq[r] = 1.0f / __shfl(rs, 4 * G + r);

    #pragma unroll
    for (int n = 0; n < 8; ++n)
        #pragma unroll
        for (int r = 0; r < 4; ++r)
            ag[((b * 4096) + qb + 16 * w + 4 * G + r) * 128 + 16 * n + l15] =
                f2bf(acc[n][r] * rq[r]);
}

// ---------------------------------------------------------------- final conv + residual
// out[c][p] = sigma * sum_d wf[c][d]*ag[p][d] + x[c][p]
__global__ __launch_bounds__(256) void final_conv(const short* __restrict__ ag,
                                                  const short* __restrict__ wf_bf,
                                                  const float* __restrict__ x,
                                                  const float* __restrict__ sig,
                                                  float* __restrict__ out) {
    const int t = threadIdx.x;
    const int b = blockIdx.x >> 6;
    const int pb = (blockIdx.x & 63) << 6;
    const int lane = t & 63, w = t >> 6, G = lane >> 4, l15 = lane & 15;
    const float s = sig[0];

    short8 af[4][4];                            // wave w owns out-channels 64w..64w+63
    #pragma unroll
    for (int j = 0; j < 4; ++j)
        #pragma unroll
        for (int kt = 0; kt < 4; ++kt)
            af[j][kt] = *(const short8*)(wf_bf + (64 * w + 16 * j + l15) * 128 + 32 * kt + 8 * G);

    #pragma unroll
    for (int nt = 0; nt < 4; ++nt) {
        short8 bfr[4];
        #pragma unroll
        for (int kt = 0; kt < 4; ++kt)
            bfr[kt] = *(const short8*)(ag + ((b * 4096) + pb + 16 * nt + l15) * 128 + 32 * kt + 8 * G);
        f32x4 acc[4];
        #pragma unroll
        for (int j = 0; j < 4; ++j) acc[j] = (f32x4){0.f, 0.f, 0.f, 0.f};
        #pragma unroll
        for (int kt = 0; kt < 4; ++kt)
            #pragma unroll
            for (int j = 0; j < 4; ++j)
                acc[j] = MFMA16(af[j][kt], bfr[kt], acc[j]);
        #pragma unroll
        for (int j = 0; j < 4; ++j)
            #pragma unroll
            for (int r = 0; r < 4; ++r) {
                int c = 64 * w + 16 * j + 4 * G + r;
                int pp = pb + 16 * nt + l15;
                int idx = (b * 256 + c) * 4096 + pp;
                out[idx] = s * acc[j][r] + x[idx];
            }
    }
}

// ---------------------------------------------------------------- launch
extern "C" void kernel_launch(void* const* d_in, const int* in_sizes, int n_in,
                              void* d_out, int out_size, void* d_ws, size_t ws_size,
                              hipStream_t stream) {
    const float* x  = (const float*)d_in[0];
    const float* wt = (const float*)d_in[1];
    const float* wp = (const float*)d_in[2];
    const float* wg = (const float*)d_in[3];
    const float* wf = (const float*)d_in[4];
    const float* sg = (const float*)d_in[5];
    float* out = (float*)d_out;

    char* ws = (char*)d_ws;
    short* w_bf  = (short*)(ws);                  //   192*256*2 =    98304
    short* wf_bf = (short*)(ws + 98304);          //   256*128*2 =    65536
    short* theta = (short*)(ws + 163840);         // 16*4096*32*2 = 4194304
    short* phiF  = (short*)(ws + 4358144);        // 16*4096*32*2 = 4194304
    short* gF    = (short*)(ws + 8552448);        // 16*4096*128*2 = 16777216
    short* phi_t = (short*)(ws + 25329664);       // 16*1024*32*2 = 1048576
    short* g_cm  = (short*)(ws + 26378240);       // 16*128*1024*2 = 4194304
    short* ag    = (short*)(ws + 30572544);       // 16*4096*128*2 = 16777216
                                                  // total ~45.2 MB

    prep_w   <<<320,  256, 0, stream>>>(wt, wp, wg, wf, w_bf, wf_bf);
    proj     <<<1024, 256, 0, stream>>>(x, w_bf, theta, phiF, gF);
    pool_phi <<<2048, 256, 0, stream>>>(phiF, phi_t);
    pool_g   <<<512,  256, 0, stream>>>(gF, g_cm);
    flash    <<<1024, 256, 0, stream>>>(theta, phi_t, g_cm, ag);
    final_conv<<<1024,256, 0, stream>>>(ag, wf_bf, x, sg, out);
}

// Round 8
// 317.271 us; speedup vs baseline: 1.3468x; 1.3468x over previous
//
#include <hip/hip_runtime.h>
#include <hip/hip_bf16.h>

// SAGAN self-attention: B=16, C=256, H=W=64, HW=4096, KEYS=1024, C8=32, C2=128
// Pipeline: prep_w -> proj (theta/phi/g GEMM) -> pool_phi/pool_g (write MFMA
// fragment-order arrays) -> flash attn (all loads lane-linear) -> final conv.

typedef short short8 __attribute__((ext_vector_type(8)));
typedef short short4v __attribute__((ext_vector_type(4)));
typedef float f32x4  __attribute__((ext_vector_type(4)));

#define MFMA16(a, b, c) __builtin_amdgcn_mfma_f32_16x16x32_bf16(a, b, c, 0, 0, 0)

__device__ __forceinline__ short f2bf(float f) {
    union { float f; unsigned u; } v; v.f = f;
    unsigned r = v.u + 0x7FFFu + ((v.u >> 16) & 1u);   // RNE
    return (short)(r >> 16);
}
__device__ __forceinline__ float bf2f(short s) {
    union { unsigned u; float f; } v; v.u = ((unsigned)(unsigned short)s) << 16;
    return v.f;
}

// K=16 bf16 MFMA. A/B: 4 bf16/lane, element i -> row/col = lane&15, k = 4*(lane>>4)+i.
// Prefer BUILTINS so the compiler models MFMA hazards (inline-asm MFMA got no
// s_nop insertion and corrupted results in v2). The asm fallback exists ONLY so
// the HOST compile pass (where __has_builtin(amdgcn builtins)=false) succeeds;
// device pass selects a builtin (proven: v3 passed correctness).
#if __has_builtin(__builtin_amdgcn_mfma_f32_16x16x16bf16_1k)
__device__ __forceinline__ void mfma_k16(short4v a, short4v b, f32x4& c) {
    c = __builtin_amdgcn_mfma_f32_16x16x16bf16_1k(a, b, c, 0, 0, 0);
}
#elif __has_builtin(__builtin_amdgcn_mfma_f32_16x16x16_bf16)
__device__ __forceinline__ void mfma_k16(short4v a, short4v b, f32x4& c) {
    c = __builtin_amdgcn_mfma_f32_16x16x16_bf16(a, b, c, 0, 0, 0);
}
#else
__device__ __forceinline__ void mfma_k16(short4v a, short4v b, f32x4& c) {
    // host-pass placeholder / last-resort asm with manual hazard padding
    asm volatile("s_nop 3\n\t"
                 "v_mfma_f32_16x16x16_bf16 %0, %1, %2, %0\n\t"
                 "s_nop 7\n\t"
                 "s_nop 3"
                 : "+v"(c) : "v"(a), "v"(b));
}
#endif

// ---------------------------------------------------------------- prep_w
// w_bf [192][256] bf16: rows 0-31 theta, 32-63 phi, 64-191 g. wf_bf [256][128].
__global__ __launch_bounds__(256) void prep_w(const float* wt, const float* wp,
                                              const float* wg, const float* wf,
                                              short* w_bf, short* wf_bf) {
    int idx = blockIdx.x * 256 + threadIdx.x;
    if (idx < 192 * 256) {
        int o = idx >> 8, c = idx & 255;
        float v = (o < 32) ? wt[o * 256 + c]
                : (o < 64) ? wp[(o - 32) * 256 + c]
                           : wg[(o - 64) * 256 + c];
        w_bf[idx] = f2bf(v);
    } else {
        int j = idx - 192 * 256;
        if (j < 256 * 128) wf_bf[j] = f2bf(wf[j]);
    }
}

// ---------------------------------------------------------------- proj
// out[o][p] = sum_c W[o][c] * x[c][p] for 64-pixel tile, all 192 out-channels.
// x staged in LDS transposed to [p][c] bf16 (pitch 264 => 16B-aligned b128 reads).
__global__ __launch_bounds__(256) void proj(const float* __restrict__ x,
                                            const short* __restrict__ w_bf,
                                            short* __restrict__ theta,
                                            short* __restrict__ phiF,
                                            short* __restrict__ gF) {
    __shared__ short xl[64 * 264];
    const int t = threadIdx.x;
    const int b = blockIdx.x >> 6;
    const int pb = (blockIdx.x & 63) << 6;
    const int p = t & 63;

    // stage: each thread packs 2 channels (c0, c0+1) for its pixel, 32 iters
    #pragma unroll
    for (int i = 0; i < 32; ++i) {
        int cp = (t >> 6) + (i << 2);          // 0..127 channel-pair index
        int c0 = cp << 1;
        float v0 = x[(b * 256 + c0) * 4096 + pb + p];
        float v1 = x[(b * 256 + c0 + 1) * 4096 + pb + p];
        unsigned pk = ((unsigned)(unsigned short)f2bf(v0)) |
                      (((unsigned)(unsigned short)f2bf(v1)) << 16);
        *(unsigned*)&xl[p * 264 + c0] = pk;
    }
    __syncthreads();

    const int lane = t & 63, w = t >> 6, G = lane >> 4, l15 = lane & 15;

    short8 af[3][8];                            // wave w owns out-rows 48w..48w+47
    #pragma unroll
    for (int j = 0; j < 3; ++j) {
        int ot = 3 * w + j;
        #pragma unroll
        for (int kt = 0; kt < 8; ++kt)
            af[j][kt] = *(const short8*)(w_bf + (16 * ot + l15) * 256 + 32 * kt + 8 * G);
    }
    f32x4 acc[3][4];
    #pragma unroll
    for (int j = 0; j < 3; ++j)
        #pragma unroll
        for (int n = 0; n < 4; ++n) acc[j][n] = (f32x4){0.f, 0.f, 0.f, 0.f};

    #pragma unroll
    for (int nt = 0; nt < 4; ++nt) {
        #pragma unroll
        for (int kt = 0; kt < 8; ++kt) {
            short8 bfr = *(const short8*)(xl + (16 * nt + l15) * 264 + 32 * kt + 8 * G);
            #pragma unroll
            for (int j = 0; j < 3; ++j)
                acc[j][nt] = MFMA16(af[j][kt], bfr, acc[j][nt]);
        }
    }

    // epilogue: D layout col=lane&15 (pixel), row=4G+r (out-channel)
    #pragma unroll
    for (int j = 0; j < 3; ++j) {
        int ot = 3 * w + j;
        #pragma unroll
        for (int nt = 0; nt < 4; ++nt) {
            int pp = pb + 16 * nt + l15;
            #pragma unroll
            for (int r = 0; r < 4; ++r) {
                int o = 16 * ot + 4 * G + r;
                short v = f2bf(acc[j][nt][r]);
                if (o < 32)      theta[(b * 4096 + pp) * 32 + o] = v;
                else if (o < 64) phiF [(b * 4096 + pp) * 32 + (o - 32)] = v;
                else             gF   [(b * 4096 + pp) * 128 + (o - 64)] = v;
            }
        }
    }
}

// ---------------------------------------------------------------- pool_phi
// phiF [b][4096][32] -> phi_frag [b][kc=64][lane=64][i=8]: QK A-frag order.
// Fragment for key chunk kc, lane (l15,G), elem i = phi[key=16kc+l15][c=8G+i].
__global__ __launch_bounds__(256) void pool_phi(const short* __restrict__ phiF,
                                                short* __restrict__ phi_frag) {
    int t = threadIdx.x;
    int b = blockIdx.x >> 7;
    int kg = blockIdx.x & 127;
    int c = t & 31;
    int ko = kg * 8 + (t >> 5);
    int kh = ko >> 5, kw = ko & 31;
    int p00 = kh * 128 + kw * 2;
    const short* base = phiF + (b * 4096 + p00) * 32 + c;
    float m = bf2f(base[0]);
    m = fmaxf(m, bf2f(base[32]));
    m = fmaxf(m, bf2f(base[64 * 32]));
    m = fmaxf(m, bf2f(base[65 * 32]));
    int kc = ko >> 4;
    int lane = (ko & 15) + 16 * (c >> 3);
    int i = c & 7;
    phi_frag[((b * 64 + kc) * 64 + lane) * 8 + i] = f2bf(m);
}

// ---------------------------------------------------------------- pool_g
// gF [b][4096][128] -> g_frag [b][kc=64][n=8][lane=64][i=4]: PV K16 B-frag order.
// Fragment kc,n, lane (l15,G), elem i = g[key=16kc+4G+i][d=16n+l15].
__global__ __launch_bounds__(256) void pool_g(const short* __restrict__ gF,
                                              short* __restrict__ g_frag) {
    int t = threadIdx.x;
    int b = blockIdx.x >> 5;
    int kh = blockIdx.x & 31;
    int d = t & 127;
    int half = t >> 7;
    int n = d >> 4, l15 = d & 15;
    #pragma unroll
    for (int it = 0; it < 16; ++it) {
        int kw = it * 2 + half;
        int p00 = kh * 128 + kw * 2;
        const short* base = gF + (b * 4096 + p00) * 128 + d;
        float m = bf2f(base[0]);
        m = fmaxf(m, bf2f(base[128]));
        m = fmaxf(m, bf2f(base[64 * 128]));
        m = fmaxf(m, bf2f(base[65 * 128]));
        int kc = 2 * kh + (kw >> 4);
        int lane = l15 + 16 * ((kw >> 2) & 3);
        int i = kw & 3;
        g_frag[(((b * 64 + kc) * 8 + n) * 64 + lane) * 4 + i] = f2bf(m);
    }
}

// ---------------------------------------------------------------- flash (v4: coalesced frag streams)
// Swapped QK^T: S = mfma_16x16x32(A=phi-frag, B=theta). D layout puts
// P[q=l15][key=4G+r] in lane (l15,G) == A-frag of the K16 bf16 MFMA.
// exp + pack -> PV directly. All loads are lane-linear (frag arrays),
// 1-deep prefetch; no LDS, no gathers, no shuffles in the loop.
__global__ __launch_bounds__(256, 4) void flash(const short* __restrict__ theta,
                                                const short* __restrict__ phi_frag,
                                                const short* __restrict__ g_frag,
                                                short* __restrict__ ag) {
    const int t = threadIdx.x;
    const int b = blockIdx.x >> 6;
    const int qb = (blockIdx.x & 63) << 6;
    const int lane = t & 63, w = t >> 6, G = lane >> 4, l15 = lane & 15;

    // theta as B-frag: lane l15 = q col, c = 8G..8G+7 (one-time gather, negligible)
    const short8 tb = *(const short8*)(theta + ((b * 4096) + qb + 16 * w + l15) * 32 + 8 * G);

    f32x4 acc[8];
    #pragma unroll
    for (int n = 0; n < 8; ++n) acc[n] = (f32x4){0.f, 0.f, 0.f, 0.f};
    float rs = 0.f;
    const f32x4 z = {0.f, 0.f, 0.f, 0.f};

    const short* pF = phi_frag + (b * 64) * 512 + lane * 8;     // + kc*512
    const short* gFr = g_frag + (b * 64) * 2048 + lane * 4;     // + kc*2048 + n*256

    // prologue: prefetch chunk 0
    short8 pf = *(const short8*)(pF);
    short4v gb[8];
    #pragma unroll
    for (int n = 0; n < 8; ++n) gb[n] = *(const short4v*)(gFr + n * 256);

    #pragma unroll 2
    for (int kc = 0; kc < 64; ++kc) {
        const int kn = (kc + 1) & 63;            // wraps to 0 on last iter (harmless)
        short8 pf_n = *(const short8*)(pF + kn * 512);
        short4v gb_n[8];
        #pragma unroll
        for (int n = 0; n < 8; ++n) gb_n[n] = *(const short4v*)(gFr + kn * 2048 + n * 256);

        // S for 16 keys: lane (l15,G) gets P[q=l15][k=4G+r]
        f32x4 s = MFMA16(pf, tb, z);
        float e0 = __expf(s[0]);
        float e1 = __expf(s[1]);
        float e2 = __expf(s[2]);
        float e3 = __expf(s[3]);
        rs += (e0 + e1) + (e2 + e3);
        short4v p4;                              // P A-frag, compiler-visible pack
        p4[0] = f2bf(e0);
        p4[1] = f2bf(e1);
        p4[2] = f2bf(e2);
        p4[3] = f2bf(e3);

        #pragma unroll
        for (int n = 0; n < 8; ++n) mfma_k16(p4, gb[n], acc[n]);

        pf = pf_n;
        #pragma unroll
        for (int n = 0; n < 8; ++n) gb[n] = gb_n[n];
    }

    // row-sum: combine the 4 G-groups holding query l15
    rs += __shfl_xor(rs, 16);
    rs += __shfl_xor(rs, 32);
    // acc D-layout holds rows q = 4G+r -> gather those sums (lane 4G+r has l15==4G+r)
    float rq[4];
    #pragma unroll
    for (int r = 0; r < 4; ++r) rq[r] = 1.0f / __shfl(rs, 4 * G + r);

    #pragma unroll
    for (int n = 0; n < 8; ++n)
        #pragma unroll
        for (int r = 0; r < 4; ++r)
            ag[((b * 4096) + qb + 16 * w + 4 * G + r) * 128 + 16 * n + l15] =
                f2bf(acc[n][r] * rq[r]);
}

// ---------------------------------------------------------------- final conv + residual
// out[c][p] = sigma * sum_d wf[c][d]*ag[p][d] + x[c][p]
__global__ __launch_bounds__(256) void final_conv(const short* __restrict__ ag,
                                                  const short* __restrict__ wf_bf,
                                                  const float* __restrict__ x,
                                                  const float* __restrict__ sig,
                                                  float* __restrict__ out) {
    const int t = threadIdx.x;
    const int b = blockIdx.x >> 6;
    const int pb = (blockIdx.x & 63) << 6;
    const int lane = t & 63, w = t >> 6, G = lane >> 4, l15 = lane & 15;
    const float s = sig[0];

    short8 af[4][4];                            // wave w owns out-channels 64w..64w+63
    #pragma unroll
    for (int j = 0; j < 4; ++j)
        #pragma unroll
        for (int kt = 0; kt < 4; ++kt)
            af[j][kt] = *(const short8*)(wf_bf + (64 * w + 16 * j + l15) * 128 + 32 * kt + 8 * G);

    #pragma unroll
    for (int nt = 0; nt < 4; ++nt) {
        short8 bfr[4];
        #pragma unroll
        for (int kt = 0; kt < 4; ++kt)
            bfr[kt] = *(const short8*)(ag + ((b * 4096) + pb + 16 * nt + l15) * 128 + 32 * kt + 8 * G);
        f32x4 acc[4];
        #pragma unroll
        for (int j = 0; j < 4; ++j) acc[j] = (f32x4){0.f, 0.f, 0.f, 0.f};
        #pragma unroll
        for (int kt = 0; kt < 4; ++kt)
            #pragma unroll
            for (int j = 0; j < 4; ++j)
                acc[j] = MFMA16(af[j][kt], bfr[kt], acc[j]);
        #pragma unroll
        for (int j = 0; j < 4; ++j)
            #pragma unroll
            for (int r = 0; r < 4; ++r) {
                int c = 64 * w + 16 * j + 4 * G + r;
                int pp = pb + 16 * nt + l15;
                int idx = (b * 256 + c) * 4096 + pp;
                out[idx] = s * acc[j][r] + x[idx];
            }
    }
}

// ---------------------------------------------------------------- launch
extern "C" void kernel_launch(void* const* d_in, const int* in_sizes, int n_in,
                              void* d_out, int out_size, void* d_ws, size_t ws_size,
                              hipStream_t stream) {
    const float* x  = (const float*)d_in[0];
    const float* wt = (const float*)d_in[1];
    const float* wp = (const float*)d_in[2];
    const float* wg = (const float*)d_in[3];
    const float* wf = (const float*)d_in[4];
    const float* sg = (const float*)d_in[5];
    float* out = (float*)d_out;

    char* ws = (char*)d_ws;
    short* w_bf     = (short*)(ws);                  //   192*256*2 =    98304
    short* wf_bf    = (short*)(ws + 98304);          //   256*128*2 =    65536
    short* theta    = (short*)(ws + 163840);         // 16*4096*32*2 = 4194304
    short* phiF     = (short*)(ws + 4358144);        // 16*4096*32*2 = 4194304
    short* gF       = (short*)(ws + 8552448);        // 16*4096*128*2 = 16777216
    short* phi_frag = (short*)(ws + 25329664);       // 16*64*64*8*2 = 1048576
    short* g_frag   = (short*)(ws + 26378240);       // 16*64*8*64*4*2 = 4194304
    short* ag       = (short*)(ws + 30572544);       // 16*4096*128*2 = 16777216
                                                     // total ~45.2 MB

    prep_w   <<<320,  256, 0, stream>>>(wt, wp, wg, wf, w_bf, wf_bf);
    proj     <<<1024, 256, 0, stream>>>(x, w_bf, theta, phiF, gF);
    pool_phi <<<2048, 256, 0, stream>>>(phiF, phi_frag);
    pool_g   <<<512,  256, 0, stream>>>(gF, g_frag);
    flash    <<<1024, 256, 0, stream>>>(theta, phi_frag, g_frag, ag);
    final_conv<<<1024,256, 0, stream>>>(ag, wf_bf, x, sg, out);
}

// Round 9
// 222.555 us; speedup vs baseline: 1.9200x; 1.4256x over previous
//
#include <hip/hip_runtime.h>
#include <hip/hip_bf16.h>

// SAGAN self-attention: B=16, C=256, H=W=64, HW=4096, KEYS=1024, C8=32, C2=128
// Pipeline: prep_w -> proj -> pool_phi/pool_g (write ONE combined per-chunk
// fragment record) -> flash (LDS-broadcast staged, dbuf) -> final conv.

typedef short short8 __attribute__((ext_vector_type(8)));
typedef short short4v __attribute__((ext_vector_type(4)));
typedef float f32x4  __attribute__((ext_vector_type(4)));

#define MFMA16(a, b, c) __builtin_amdgcn_mfma_f32_16x16x32_bf16(a, b, c, 0, 0, 0)

__device__ __forceinline__ short f2bf(float f) {
    union { float f; unsigned u; } v; v.f = f;
    unsigned r = v.u + 0x7FFFu + ((v.u >> 16) & 1u);   // RNE
    return (short)(r >> 16);
}
__device__ __forceinline__ float bf2f(short s) {
    union { unsigned u; float f; } v; v.u = ((unsigned)(unsigned short)s) << 16;
    return v.f;
}

// K=16 bf16 MFMA. A/B: 4 bf16/lane, elem i -> row/col = lane&15, k = 4*(lane>>4)+i.
// Builtins preferred (compiler models MFMA hazards; raw asm corrupted v2).
// The #else asm exists only so the HOST pass (no amdgcn builtins) compiles.
#if __has_builtin(__builtin_amdgcn_mfma_f32_16x16x16bf16_1k)
__device__ __forceinline__ void mfma_k16(short4v a, short4v b, f32x4& c) {
    c = __builtin_amdgcn_mfma_f32_16x16x16bf16_1k(a, b, c, 0, 0, 0);
}
#elif __has_builtin(__builtin_amdgcn_mfma_f32_16x16x16_bf16)
__device__ __forceinline__ void mfma_k16(short4v a, short4v b, f32x4& c) {
    c = __builtin_amdgcn_mfma_f32_16x16x16_bf16(a, b, c, 0, 0, 0);
}
#else
__device__ __forceinline__ void mfma_k16(short4v a, short4v b, f32x4& c) {
    asm volatile("s_nop 3\n\t"
                 "v_mfma_f32_16x16x16_bf16 %0, %1, %2, %0\n\t"
                 "s_nop 7\n\t"
                 "s_nop 3"
                 : "+v"(c) : "v"(a), "v"(b));
}
#endif

// async global->LDS, 16B per lane, linear dest (base + lane*16) — rule #21 safe.
__device__ __forceinline__ void gload_lds16(const short* g, short* l) {
#if __has_builtin(__builtin_amdgcn_global_load_lds)
    __builtin_amdgcn_global_load_lds(
        (const __attribute__((address_space(1))) void*)g,
        (__attribute__((address_space(3))) void*)l, 16, 0, 0);
#endif
}

// ---------------------------------------------------------------- prep_w
// w_bf [192][256] bf16: rows 0-31 theta, 32-63 phi, 64-191 g. wf_bf [256][128].
__global__ __launch_bounds__(256) void prep_w(const float* wt, const float* wp,
                                              const float* wg, const float* wf,
                                              short* w_bf, short* wf_bf) {
    int idx = blockIdx.x * 256 + threadIdx.x;
    if (idx < 192 * 256) {
        int o = idx >> 8, c = idx & 255;
        float v = (o < 32) ? wt[o * 256 + c]
                : (o < 64) ? wp[(o - 32) * 256 + c]
                           : wg[(o - 64) * 256 + c];
        w_bf[idx] = f2bf(v);
    } else {
        int j = idx - 192 * 256;
        if (j < 256 * 128) wf_bf[j] = f2bf(wf[j]);
    }
}

// ---------------------------------------------------------------- proj
// out[o][p] = sum_c W[o][c] * x[c][p] for 64-pixel tile, all 192 out-channels.
// x staged in LDS transposed to [p][c] bf16 (pitch 264 => 16B-aligned b128 reads).
__global__ __launch_bounds__(256) void proj(const float* __restrict__ x,
                                            const short* __restrict__ w_bf,
                                            short* __restrict__ theta,
                                            short* __restrict__ phiF,
                                            short* __restrict__ gF) {
    __shared__ short xl[64 * 264];
    const int t = threadIdx.x;
    const int b = blockIdx.x >> 6;
    const int pb = (blockIdx.x & 63) << 6;
    const int p = t & 63;

    #pragma unroll
    for (int i = 0; i < 32; ++i) {
        int cp = (t >> 6) + (i << 2);
        int c0 = cp << 1;
        float v0 = x[(b * 256 + c0) * 4096 + pb + p];
        float v1 = x[(b * 256 + c0 + 1) * 4096 + pb + p];
        unsigned pk = ((unsigned)(unsigned short)f2bf(v0)) |
                      (((unsigned)(unsigned short)f2bf(v1)) << 16);
        *(unsigned*)&xl[p * 264 + c0] = pk;
    }
    __syncthreads();

    const int lane = t & 63, w = t >> 6, G = lane >> 4, l15 = lane & 15;

    short8 af[3][8];
    #pragma unroll
    for (int j = 0; j < 3; ++j) {
        int ot = 3 * w + j;
        #pragma unroll
        for (int kt = 0; kt < 8; ++kt)
            af[j][kt] = *(const short8*)(w_bf + (16 * ot + l15) * 256 + 32 * kt + 8 * G);
    }
    f32x4 acc[3][4];
    #pragma unroll
    for (int j = 0; j < 3; ++j)
        #pragma unroll
        for (int n = 0; n < 4; ++n) acc[j][n] = (f32x4){0.f, 0.f, 0.f, 0.f};

    #pragma unroll
    for (int nt = 0; nt < 4; ++nt) {
        #pragma unroll
        for (int kt = 0; kt < 8; ++kt) {
            short8 bfr = *(const short8*)(xl + (16 * nt + l15) * 264 + 32 * kt + 8 * G);
            #pragma unroll
            for (int j = 0; j < 3; ++j)
                acc[j][nt] = MFMA16(af[j][kt], bfr, acc[j][nt]);
        }
    }

    #pragma unroll
    for (int j = 0; j < 3; ++j) {
        int ot = 3 * w + j;
        #pragma unroll
        for (int nt = 0; nt < 4; ++nt) {
            int pp = pb + 16 * nt + l15;
            #pragma unroll
            for (int r = 0; r < 4; ++r) {
                int o = 16 * ot + 4 * G + r;
                short v = f2bf(acc[j][nt][r]);
                if (o < 32)      theta[(b * 4096 + pp) * 32 + o] = v;
                else if (o < 64) phiF [(b * 4096 + pp) * 32 + (o - 32)] = v;
                else             gF   [(b * 4096 + pp) * 128 + (o - 64)] = v;
            }
        }
    }
}

// ---------------------------------------------------------------- pool_phi
// phiF [b][4096][32] -> frag[b][kc] bytes [0,1024): QK A-frag, lane l: 8 bf16.
// frag chunk stride = 2560 shorts (5120 B).
__global__ __launch_bounds__(256) void pool_phi(const short* __restrict__ phiF,
                                                short* __restrict__ frag) {
    int t = threadIdx.x;
    int b = blockIdx.x >> 7;
    int kg = blockIdx.x & 127;
    int c = t & 31;
    int ko = kg * 8 + (t >> 5);
    int kh = ko >> 5, kw = ko & 31;
    int p00 = kh * 128 + kw * 2;
    const short* base = phiF + (b * 4096 + p00) * 32 + c;
    float m = bf2f(base[0]);
    m = fmaxf(m, bf2f(base[32]));
    m = fmaxf(m, bf2f(base[64 * 32]));
    m = fmaxf(m, bf2f(base[65 * 32]));
    int kc = ko >> 4;
    int lane = (ko & 15) + 16 * (c >> 3);
    int i = c & 7;
    frag[(b * 64 + kc) * 2560 + lane * 8 + i] = f2bf(m);
}

// ---------------------------------------------------------------- pool_g
// gF [b][4096][128] -> frag[b][kc] bytes [1024,5120): PV K16 B-frags,
// n=0..7 sections of 512 B; lane l: 4 bf16 = g[key=16kc+4G+i][d=16n+l15].
__global__ __launch_bounds__(256) void pool_g(const short* __restrict__ gF,
                                              short* __restrict__ frag) {
    int t = threadIdx.x;
    int b = blockIdx.x >> 5;
    int kh = blockIdx.x & 31;
    int d = t & 127;
    int half = t >> 7;
    int n = d >> 4, l15 = d & 15;
    #pragma unroll
    for (int it = 0; it < 16; ++it) {
        int kw = it * 2 + half;
        int p00 = kh * 128 + kw * 2;
        const short* base = gF + (b * 4096 + p00) * 128 + d;
        float m = bf2f(base[0]);
        m = fmaxf(m, bf2f(base[128]));
        m = fmaxf(m, bf2f(base[64 * 128]));
        m = fmaxf(m, bf2f(base[65 * 128]));
        int kc = 2 * kh + (kw >> 4);
        int lane = l15 + 16 * ((kw >> 2) & 3);
        int i = kw & 3;
        frag[(b * 64 + kc) * 2560 + 512 + n * 256 + lane * 4 + i] = f2bf(m);
    }
}

// ---------------------------------------------------------------- flash (v5: LDS broadcast staging)
// All 4 waves (and all 64 q-blocks per batch) consume the SAME frag stream ->
// stage each 5120B chunk once per block into LDS (global_load_lds, dbuf),
// ds_read broadcast it. Swapped QK^T (S lane layout == K16 A-frag), exp+pack
// in regs, PV via K16 MFMA. One barrier per iter (its vmcnt drain completes
// the stage and closes the dbuf hazard).
__global__ __launch_bounds__(256, 4) void flash(const short* __restrict__ theta,
                                                const short* __restrict__ frag,
                                                short* __restrict__ ag) {
    __shared__ short fbuf[2][2560];
    const int t = threadIdx.x;
    const int b = blockIdx.x >> 6;
    const int qb = (blockIdx.x & 63) << 6;
    const int lane = t & 63, w = t >> 6, G = lane >> 4, l15 = lane & 15;

    const short8 tb = *(const short8*)(theta + ((b * 4096) + qb + 16 * w + l15) * 32 + 8 * G);

    f32x4 acc[8];
    #pragma unroll
    for (int n = 0; n < 8; ++n) acc[n] = (f32x4){0.f, 0.f, 0.f, 0.f};
    float rs = 0.f;
    const f32x4 z = {0.f, 0.f, 0.f, 0.f};

    const short* src = frag + (size_t)(b * 64) * 2560;

    // stage chunk kc into fbuf[bi]: wave w covers bytes [w*1024,(w+1)*1024),
    // wave 0 also covers [4096,5120). dest is linear base+lane*16.
    #define STAGE(bi, kc)  do {                                               \
        const short* g_ = src + (kc) * 2560 + w * 512 + lane * 8;             \
        gload_lds16(g_, &fbuf[bi][w * 512]);                                  \
        if (w == 0) gload_lds16(src + (kc) * 2560 + 2048 + lane * 8,          \
                                &fbuf[bi][2048]);                             \
    } while (0)

    STAGE(0, 0);
    __syncthreads();                      // drains vmcnt -> fbuf[0] ready

    for (int kc = 0; kc < 64; ++kc) {
        const int cur = kc & 1;
        if (kc < 63) STAGE(cur ^ 1, kc + 1);

        // broadcast ds_reads of current chunk
        short8 pf = *(const short8*)&fbuf[cur][lane * 8];
        short4v gb[8];
        #pragma unroll
        for (int n = 0; n < 8; ++n)
            gb[n] = *(const short4v*)&fbuf[cur][512 + n * 256 + lane * 4];

        f32x4 s = MFMA16(pf, tb, z);
        float e0 = __expf(s[0]);
        float e1 = __expf(s[1]);
        float e2 = __expf(s[2]);
        float e3 = __expf(s[3]);
        rs += (e0 + e1) + (e2 + e3);
        short4v p4;
        p4[0] = f2bf(e0);
        p4[1] = f2bf(e1);
        p4[2] = f2bf(e2);
        p4[3] = f2bf(e3);

        #pragma unroll
        for (int n = 0; n < 8; ++n) mfma_k16(p4, gb[n], acc[n]);

        __syncthreads();                  // stage complete + all reads done
    }
    #undef STAGE

    // row-sum: fold the 4 G-groups of query l15, then fetch per-acc-row sums
    rs += __shfl_xor(rs, 16);
    rs += __shfl_xor(rs, 32);
    float rq[4];
    #pragma unroll
    for (int r = 0; r < 4; ++r) rq[r] = 1.0f / __shfl(rs, 4 * G + r);

    #pragma unroll
    for (int n = 0; n < 8; ++n)
        #pragma unroll
        for (int r = 0; r < 4; ++r)
            ag[((b * 4096) + qb + 16 * w + 4 * G + r) * 128 + 16 * n + l15] =
                f2bf(acc[n][r] * rq[r]);
}

// ---------------------------------------------------------------- final conv + residual
// out[c][p] = sigma * sum_d wf[c][d]*ag[p][d] + x[c][p]
__global__ __launch_bounds__(256) void final_conv(const short* __restrict__ ag,
                                                  const short* __restrict__ wf_bf,
                                                  const float* __restrict__ x,
                                                  const float* __restrict__ sig,
                                                  float* __restrict__ out) {
    const int t = threadIdx.x;
    const int b = blockIdx.x >> 6;
    const int pb = (blockIdx.x & 63) << 6;
    const int lane = t & 63, w = t >> 6, G = lane >> 4, l15 = lane & 15;
    const float s = sig[0];

    short8 af[4][4];
    #pragma unroll
    for (int j = 0; j < 4; ++j)
        #pragma unroll
        for (int kt = 0; kt < 4; ++kt)
            af[j][kt] = *(const short8*)(wf_bf + (64 * w + 16 * j + l15) * 128 + 32 * kt + 8 * G);

    #pragma unroll
    for (int nt = 0; nt < 4; ++nt) {
        short8 bfr[4];
        #pragma unroll
        for (int kt = 0; kt < 4; ++kt)
            bfr[kt] = *(const short8*)(ag + ((b * 4096) + pb + 16 * nt + l15) * 128 + 32 * kt + 8 * G);
        f32x4 acc[4];
        #pragma unroll
        for (int j = 0; j < 4; ++j) acc[j] = (f32x4){0.f, 0.f, 0.f, 0.f};
        #pragma unroll
        for (int kt = 0; kt < 4; ++kt)
            #pragma unroll
            for (int j = 0; j < 4; ++j)
                acc[j] = MFMA16(af[j][kt], bfr[kt], acc[j]);
        #pragma unroll
        for (int j = 0; j < 4; ++j)
            #pragma unroll
            for (int r = 0; r < 4; ++r) {
                int c = 64 * w + 16 * j + 4 * G + r;
                int pp = pb + 16 * nt + l15;
                int idx = (b * 256 + c) * 4096 + pp;
                out[idx] = s * acc[j][r] + x[idx];
            }
    }
}

// ---------------------------------------------------------------- launch
extern "C" void kernel_launch(void* const* d_in, const int* in_sizes, int n_in,
                              void* d_out, int out_size, void* d_ws, size_t ws_size,
                              hipStream_t stream) {
    const float* x  = (const float*)d_in[0];
    const float* wt = (const float*)d_in[1];
    const float* wp = (const float*)d_in[2];
    const float* wg = (const float*)d_in[3];
    const float* wf = (const float*)d_in[4];
    const float* sg = (const float*)d_in[5];
    float* out = (float*)d_out;

    char* ws = (char*)d_ws;
    short* w_bf  = (short*)(ws);                  //   192*256*2 =    98304
    short* wf_bf = (short*)(ws + 98304);          //   256*128*2 =    65536
    short* theta = (short*)(ws + 163840);         // 16*4096*32*2 = 4194304
    short* phiF  = (short*)(ws + 4358144);        // 16*4096*32*2 = 4194304
    short* gF    = (short*)(ws + 8552448);        // 16*4096*128*2 = 16777216
    short* frag  = (short*)(ws + 25329664);       // 16*64*2560*2 = 5242880
    short* ag    = (short*)(ws + 30572544);       // 16*4096*128*2 = 16777216
                                                  // total ~45.2 MB

    prep_w   <<<320,  256, 0, stream>>>(wt, wp, wg, wf, w_bf, wf_bf);
    proj     <<<1024, 256, 0, stream>>>(x, w_bf, theta, phiF, gF);
    pool_phi <<<2048, 256, 0, stream>>>(phiF, frag);
    pool_g   <<<512,  256, 0, stream>>>(gF, frag);
    flash    <<<1024, 256, 0, stream>>>(theta, frag, ag);
    final_conv<<<1024,256, 0, stream>>>(ag, wf_bf, x, sg, out);
}